// Round 2
// baseline (423.110 us; speedup 1.0000x reference)
//
#include <hip/hip_runtime.h>

typedef unsigned short u16;
typedef __attribute__((ext_vector_type(8))) __bf16 bf16x8;
typedef __attribute__((ext_vector_type(4))) float f32x4;

#define D_MODEL 2048
#define SEQ 2048
#define NHEAD 16
#define HDIM 128

#define AS1 __attribute__((address_space(1)))
#define AS3 __attribute__((address_space(3)))
#define GL2LDS(g, l) __builtin_amdgcn_global_load_lds((AS1 const void*)(g), (AS3 void*)(l), 16, 0, 0)

__device__ __forceinline__ u16 f2bf(float f) {
  unsigned u = __float_as_uint(f);
  u += 0x7fff + ((u >> 16) & 1);   // RNE
  return (u16)(u >> 16);
}
__device__ __forceinline__ float bf2f(u16 h) {
  return __uint_as_float(((unsigned)h) << 16);
}
__device__ __forceinline__ float fexp2(float x) {
#if __has_builtin(__builtin_amdgcn_exp2f)
  return __builtin_amdgcn_exp2f(x);
#else
  return __expf(x * 0.69314718055994531f);
#endif
}

// ---------------- fused fp32 -> bf16 casts (7 tensors, one launch) ----------------
__global__ __launch_bounds__(256) void k_cast7(const float* i0, const float* i1, const float* i2,
                                               const float* i3, const float* i4, const float* i5,
                                               const float* i6,
                                               u16* o0, u16* o1, u16* o2, u16* o3, u16* o4,
                                               u16* o5, u16* o6) {
  const float* in; u16* out;
  switch (blockIdx.y) {
    case 0: in = i0; out = o0; break;
    case 1: in = i1; out = o1; break;
    case 2: in = i2; out = o2; break;
    case 3: in = i3; out = o3; break;
    case 4: in = i4; out = o4; break;
    case 5: in = i5; out = o5; break;
    default: in = i6; out = o6; break;
  }
  const int i = blockIdx.x * blockDim.x + threadIdx.x;
  const float4 v = reinterpret_cast<const float4*>(in)[i];
  ushort4 o;
  o.x = f2bf(v.x); o.y = f2bf(v.y); o.z = f2bf(v.z); o.w = f2bf(v.w);
  reinterpret_cast<ushort4*>(out)[i] = o;
}

// ---------------- NT GEMM: C[m,n] = sum_k A[m,k]*B[n,k], 2048^3, 128x128 tile ----------------
// outmode: 0 = bf16 row-major, 1 = f32 row-major, 2 = bf16 TRANSPOSED (C^T, i.e. out[n][m])
__device__ __forceinline__ void gemm_nt_body(const u16* __restrict__ A, const u16* __restrict__ B,
                                             void* __restrict__ C, u16* As, u16* Bs, int outmode) {
  const int tn = blockIdx.x, tm = blockIdx.y;
  const int t = threadIdx.x;
  const int lane = t & 63, w = t >> 6;
  const int wr = w >> 1, wc = w & 1;
  const int lrow = lane & 15, lk = (lane >> 4) * 8;
  f32x4 acc[4][4] = {};
  for (int kt = 0; kt < D_MODEL; kt += 64) {
#pragma unroll
    for (int c = 0; c < 4; ++c) {
      const int elem = c * 2048 + t * 8;     // flat bf16 index into 128x64 tile
      const int r = elem >> 6, col = elem & 63;
      GL2LDS(A + (size_t)(tm * 128 + r) * D_MODEL + kt + col, As + c * 2048 + w * 512);
      GL2LDS(B + (size_t)(tn * 128 + r) * D_MODEL + kt + col, Bs + c * 2048 + w * 512);
    }
    __syncthreads();
#pragma unroll
    for (int kk = 0; kk < 2; ++kk) {
      bf16x8 af[4], bfr[4];
#pragma unroll
      for (int i = 0; i < 4; ++i) {
        af[i]  = *(const bf16x8*)(As + (wr * 64 + i * 16 + lrow) * 64 + kk * 32 + lk);
        bfr[i] = *(const bf16x8*)(Bs + (wc * 64 + i * 16 + lrow) * 64 + kk * 32 + lk);
      }
#pragma unroll
      for (int i = 0; i < 4; ++i)
#pragma unroll
        for (int j = 0; j < 4; ++j)
          acc[i][j] = __builtin_amdgcn_mfma_f32_16x16x32_bf16(af[i], bfr[j], acc[i][j], 0, 0, 0);
    }
    __syncthreads();
  }
  // C layout (measured m89): col = lane&15, row = (lane>>4)*4 + reg
  const int crow0 = tm * 128 + wr * 64 + (lane >> 4) * 4;
  const int ccol0 = tn * 128 + wc * 64 + lrow;
  if (outmode == 2) {
    // transposed store: out[col][row], 4 consecutive rows per lane -> ushort4
#pragma unroll
    for (int i = 0; i < 4; ++i)
#pragma unroll
      for (int j = 0; j < 4; ++j) {
        ushort4 o;
        o.x = f2bf(acc[i][j][0]); o.y = f2bf(acc[i][j][1]);
        o.z = f2bf(acc[i][j][2]); o.w = f2bf(acc[i][j][3]);
        *(ushort4*)((u16*)C + (size_t)(ccol0 + j * 16) * D_MODEL + crow0 + i * 16) = o;
      }
  } else {
#pragma unroll
    for (int i = 0; i < 4; ++i)
#pragma unroll
      for (int j = 0; j < 4; ++j)
#pragma unroll
        for (int r = 0; r < 4; ++r) {
          const size_t idx = (size_t)(crow0 + i * 16 + r) * D_MODEL + ccol0 + j * 16;
          if (outmode == 0) ((u16*)C)[idx] = f2bf(acc[i][j][r]);
          else              ((float*)C)[idx] = acc[i][j][r];
        }
  }
}

__global__ __launch_bounds__(256) void k_gemm_qkv(const u16* Xq, const u16* Xk, const u16* Xv,
                                                  const u16* Wq, const u16* Wk, const u16* Wv,
                                                  u16* Q, u16* K, u16* VT) {
  __shared__ u16 As[128 * 64], Bs[128 * 64];
  const int z = blockIdx.z;
  const u16* A = (z == 0) ? Xq : (z == 1) ? Xk : Xv;
  const u16* B = (z == 0) ? Wq : (z == 1) ? Wk : Wv;
  u16* C = (z == 0) ? Q : (z == 1) ? K : VT;
  gemm_nt_body(A, B, C, As, Bs, (z == 2) ? 2 : 0);
}

__global__ __launch_bounds__(256) void k_gemm_out(const u16* A, const u16* B, float* C) {
  __shared__ u16 As[128 * 64], Bs[128 * 64];
  gemm_nt_body(A, B, C, As, Bs, 1);
}

// ---------------- RoPE (rotate_half); Q gets log2(e)/sqrt(hd) for exp2-domain softmax ----------------
__global__ __launch_bounds__(256) void k_rope(u16* Q, u16* K) {
  const int idx = blockIdx.x * blockDim.x + threadIdx.x; // 0 .. SEQ*NHEAD*64-1
  u16* X = blockIdx.y ? K : Q;
  const float scale = blockIdx.y ? 1.0f : (1.4426950408889634f * 0.08838834764831845f);
  const int s = idx >> 10;
  const int h = (idx >> 6) & 15;
  const int j = idx & 63;
  const float freq = __expf((float)j * -0.14391156831212787f); // -ln(10000)/64
  float sn, cs;
  sincosf((float)s * freq, &sn, &cs);
  const size_t base = (size_t)s * D_MODEL + h * HDIM + j;
  const float x1 = bf2f(X[base]), x2 = bf2f(X[base + 64]);
  X[base]      = f2bf((x1 * cs - x2 * sn) * scale);
  X[base + 64] = f2bf((x2 * cs + x1 * sn) * scale);
}

// ---------------- staging: K tile [64][128] and V^T tile [128][64], XOR-swizzled ----------------
// LDS(row, chunk) holds global chunk (chunk ^ swz(row)); read applies same XOR.
__device__ __forceinline__ void stage_kv(u16* Kbuf, u16* Vbuf, int tt, int h, int w, int lane,
                                         const u16* __restrict__ K, const u16* __restrict__ VT) {
  const int kvb = tt * 64;
  const int g = lane >> 4, lrow = lane & 15;
#pragma unroll
  for (int p = 0; p < 8; ++p) {
    {
      const int rk = p * 8 + w * 4 + g;             // K tile row (16 chunks/row)
      GL2LDS(K + (size_t)(kvb + rk) * D_MODEL + h * HDIM + ((lrow ^ (rk & 15)) * 8),
             Kbuf + (p * 128 + w * 64) * 8);
    }
    {
      const int rv = p * 16 + w * 8 + (lane >> 3);  // V^T tile row (8 chunks/row)
      const int cv = lane & 7;
      GL2LDS(VT + (size_t)(h * HDIM + rv) * D_MODEL + kvb + ((cv ^ (rv & 7)) * 8),
             Vbuf + (p * 128 + w * 64) * 8);
    }
  }
}

// ---------------- causal flash attention ----------------
// Grid (16 heads, 16 pairs), 128 threads = 2 waves x 32 q-rows.
// Block handles q-tiles {pj, 31-pj} (64 rows each) sequentially -> 33 kv-steps per block, balanced.
__global__ __launch_bounds__(128) void k_attn(const u16* __restrict__ Q, const u16* __restrict__ K,
                                              const u16* __restrict__ VT, u16* __restrict__ O) {
  __shared__ u16 Kb[2][64 * 128];
  __shared__ u16 Vb[2][128 * 64];
  __shared__ u16 Pl[2][32 * 72];
  const int h = blockIdx.x;       // head fastest -> same-head blocks share an XCD L2
  const int pj = blockIdx.y;
  const int t = threadIdx.x;
  const int lane = t & 63, w = t >> 6;
  const int lrow = lane & 15, g = lane >> 4, lk = g * 8;

#pragma unroll 1
  for (int side = 0; side < 2; ++side) {
    const int qt = side ? (31 - pj) : pj;     // 64-row q-tile index
    const int qrow0 = qt * 64 + w * 32;

    bf16x8 qf[2][4];
#pragma unroll
    for (int mi = 0; mi < 2; ++mi)
#pragma unroll
      for (int ks = 0; ks < 4; ++ks)
        qf[mi][ks] = *(const bf16x8*)(Q + (size_t)(qrow0 + mi * 16 + lrow) * D_MODEL + h * HDIM + ks * 32 + lk);

    f32x4 accO[2][8] = {};
    float m_run[2][4], l_run[2][4];
#pragma unroll
    for (int mi = 0; mi < 2; ++mi)
#pragma unroll
      for (int r = 0; r < 4; ++r) { m_run[mi][r] = -1e30f; l_run[mi][r] = 0.f; }

    const int nt = qt + 1;
    stage_kv(Kb[0], Vb[0], 0, h, w, lane, K, VT);
    __syncthreads();

#pragma unroll 1
    for (int tt = 0; tt < nt; ++tt) {
      const int cur = tt & 1;
      if (tt + 1 < nt) stage_kv(Kb[cur ^ 1], Vb[cur ^ 1], tt + 1, h, w, lane, K, VT);

      // S = Q K^T (32x64 per wave), swizzled K reads
      f32x4 s[2][4] = {};
#pragma unroll
      for (int ks = 0; ks < 4; ++ks) {
        bf16x8 kf[4];
#pragma unroll
        for (int ni = 0; ni < 4; ++ni) {
          const int R = ni * 16 + lrow;
          const int ch = (ks * 4 + g) ^ lrow;
          kf[ni] = *(const bf16x8*)(&Kb[cur][R * 128 + ch * 8]);
        }
#pragma unroll
        for (int mi = 0; mi < 2; ++mi)
#pragma unroll
          for (int ni = 0; ni < 4; ++ni)
            s[mi][ni] = __builtin_amdgcn_mfma_f32_16x16x32_bf16(qf[mi][ks], kf[ni], s[mi][ni], 0, 0, 0);
      }

      const int kv = tt * 64;
      if (tt == qt) {   // only the diagonal tile needs masking
#pragma unroll
        for (int mi = 0; mi < 2; ++mi)
#pragma unroll
          for (int ni = 0; ni < 4; ++ni) {
            const int colg = kv + ni * 16 + lrow;
#pragma unroll
            for (int r = 0; r < 4; ++r) {
              const int rowg = qrow0 + mi * 16 + g * 4 + r;
              if (colg > rowg) s[mi][ni][r] = -1e30f;
            }
          }
      }

      // wave-parallel online softmax in exp2 domain
#pragma unroll
      for (int mi = 0; mi < 2; ++mi)
#pragma unroll
        for (int r = 0; r < 4; ++r) {
          float pm = fmaxf(fmaxf(s[mi][0][r], s[mi][1][r]), fmaxf(s[mi][2][r], s[mi][3][r]));
          pm = fmaxf(pm, __shfl_xor(pm, 1));
          pm = fmaxf(pm, __shfl_xor(pm, 2));
          pm = fmaxf(pm, __shfl_xor(pm, 4));
          pm = fmaxf(pm, __shfl_xor(pm, 8));
          const float mo = m_run[mi][r];
          const float mn = fmaxf(mo, pm);
          const float sf = fexp2(mo - mn);
          float rs = 0.f;
#pragma unroll
          for (int ni = 0; ni < 4; ++ni) {
            const float p = fexp2(s[mi][ni][r] - mn);
            s[mi][ni][r] = p;
            rs += p;
          }
          rs += __shfl_xor(rs, 1);
          rs += __shfl_xor(rs, 2);
          rs += __shfl_xor(rs, 4);
          rs += __shfl_xor(rs, 8);
          l_run[mi][r] = l_run[mi][r] * sf + rs;
          m_run[mi][r] = mn;
#pragma unroll
          for (int dt = 0; dt < 8; ++dt) accO[mi][dt][r] *= sf;
        }

      // P (C-layout) -> per-wave LDS, read back as A-fragments
#pragma unroll
      for (int mi = 0; mi < 2; ++mi)
#pragma unroll
        for (int ni = 0; ni < 4; ++ni)
#pragma unroll
          for (int r = 0; r < 4; ++r)
            Pl[w][(mi * 16 + g * 4 + r) * 72 + ni * 16 + lrow] = f2bf(s[mi][ni][r]);
      asm volatile("s_waitcnt lgkmcnt(0)" ::: "memory");

      // O += P V, swizzled V^T reads
#pragma unroll
      for (int ns = 0; ns < 2; ++ns) {
        bf16x8 pf[2];
#pragma unroll
        for (int mi = 0; mi < 2; ++mi)
          pf[mi] = *(const bf16x8*)(&Pl[w][(mi * 16 + lrow) * 72 + ns * 32 + lk]);
#pragma unroll
        for (int dt = 0; dt < 8; ++dt) {
          const int R = dt * 16 + lrow;
          const int ch = (ns * 4 + g) ^ (lrow & 7);
          const bf16x8 vf = *(const bf16x8*)(&Vb[cur][R * 64 + ch * 8]);
#pragma unroll
          for (int mi = 0; mi < 2; ++mi)
            accO[mi][dt] = __builtin_amdgcn_mfma_f32_16x16x32_bf16(pf[mi], vf, accO[mi][dt], 0, 0, 0);
        }
      }
      __syncthreads();
    }

    // epilogue: O /= l, store bf16
#pragma unroll
    for (int mi = 0; mi < 2; ++mi)
#pragma unroll
      for (int r = 0; r < 4; ++r) {
        const float inv = 1.0f / l_run[mi][r];
        const size_t row = (size_t)(qrow0 + mi * 16 + g * 4 + r);
#pragma unroll
        for (int dt = 0; dt < 8; ++dt)
          O[row * D_MODEL + h * HDIM + dt * 16 + lrow] = f2bf(accO[mi][dt][r] * inv);
      }
  }
}

// ---------------- launch ----------------
extern "C" void kernel_launch(void* const* d_in, const int* in_sizes, int n_in,
                              void* d_out, int out_size, void* d_ws, size_t ws_size,
                              hipStream_t stream) {
  const float* query = (const float*)d_in[0];
  const float* key_  = (const float*)d_in[1];
  const float* value = (const float*)d_in[2];
  const float* Wq    = (const float*)d_in[3];
  const float* Wk    = (const float*)d_in[4];
  const float* Wv    = (const float*)d_in[5];
  const float* Wo    = (const float*)d_in[6];
  float* out = (float*)d_out;

  const size_t TS = (size_t)SEQ * D_MODEL; // 4M elems per tensor
  u16* ws  = (u16*)d_ws;
  u16* bXq = ws + 0 * TS;
  u16* bXk = ws + 1 * TS;
  u16* bXv = ws + 2 * TS;
  u16* bWq = ws + 3 * TS;
  u16* bWk = ws + 4 * TS;
  u16* bWv = ws + 5 * TS;
  u16* bWo = ws + 6 * TS;
  u16* bQ  = ws + 7 * TS;
  u16* bK  = ws + 8 * TS;
  u16* bVT = ws + 9 * TS;
  u16* bA  = ws + 10 * TS;

  const int n4 = (int)(TS / 4);
  k_cast7<<<dim3(n4 / 256, 7), 256, 0, stream>>>(query, key_, value, Wq, Wk, Wv, Wo,
                                                 bXq, bXk, bXv, bWq, bWk, bWv, bWo);

  k_gemm_qkv<<<dim3(16, 16, 3), 256, 0, stream>>>(bXq, bXk, bXv, bWq, bWk, bWv, bQ, bK, bVT);

  k_rope<<<dim3((SEQ * NHEAD * 64) / 256, 2), 256, 0, stream>>>(bQ, bK);

  k_attn<<<dim3(16, 16), 128, 0, stream>>>(bQ, bK, bVT, bA);

  k_gemm_out<<<dim3(16, 16), 256, 0, stream>>>(bA, bWo, out);
}

// Round 3
// 351.441 us; speedup vs baseline: 1.2039x; 1.2039x over previous
//
#include <hip/hip_runtime.h>

typedef unsigned short u16;
typedef __attribute__((ext_vector_type(8))) __bf16 bf16x8;
typedef __attribute__((ext_vector_type(4))) float f32x4;

#define D_MODEL 2048
#define SEQ 2048
#define NHEAD 16
#define HDIM 128

#define AS1 __attribute__((address_space(1)))
#define AS3 __attribute__((address_space(3)))
#define GL2LDS(g, l) __builtin_amdgcn_global_load_lds((AS1 const void*)(g), (AS3 void*)(l), 16, 0, 0)

__device__ __forceinline__ u16 f2bf(float f) {
  unsigned u = __float_as_uint(f);
  u += 0x7fff + ((u >> 16) & 1);   // RNE
  return (u16)(u >> 16);
}
__device__ __forceinline__ float bf2f(u16 h) {
  return __uint_as_float(((unsigned)h) << 16);
}
__device__ __forceinline__ float fexp2(float x) {
#if __has_builtin(__builtin_amdgcn_exp2f)
  return __builtin_amdgcn_exp2f(x);
#else
  return __expf(x * 0.69314718055994531f);
#endif
}

// ---------------- fused fp32 -> bf16 casts (7 tensors, one launch) ----------------
__global__ __launch_bounds__(256) void k_cast7(const float* i0, const float* i1, const float* i2,
                                               const float* i3, const float* i4, const float* i5,
                                               const float* i6,
                                               u16* o0, u16* o1, u16* o2, u16* o3, u16* o4,
                                               u16* o5, u16* o6) {
  const float* in; u16* out;
  switch (blockIdx.y) {
    case 0: in = i0; out = o0; break;
    case 1: in = i1; out = o1; break;
    case 2: in = i2; out = o2; break;
    case 3: in = i3; out = o3; break;
    case 4: in = i4; out = o4; break;
    case 5: in = i5; out = o5; break;
    default: in = i6; out = o6; break;
  }
  const int i = blockIdx.x * blockDim.x + threadIdx.x;
  const float4 v = reinterpret_cast<const float4*>(in)[i];
  ushort4 o;
  o.x = f2bf(v.x); o.y = f2bf(v.y); o.z = f2bf(v.z); o.w = f2bf(v.w);
  reinterpret_cast<ushort4*>(out)[i] = o;
}

// ---------------- NT GEMM: C[m,n] = sum_k A[m,k]*B[n,k], 128x128 tile ----------------
// outmode: 0 = bf16 row-major, 2 = bf16 TRANSPOSED (out[n][m])
__device__ __forceinline__ void gemm_nt_body(const u16* __restrict__ A, const u16* __restrict__ B,
                                             void* __restrict__ C, u16* As, u16* Bs, int outmode) {
  const int tn = blockIdx.x, tm = blockIdx.y;
  const int t = threadIdx.x;
  const int lane = t & 63, w = t >> 6;
  const int wr = w >> 1, wc = w & 1;
  const int lrow = lane & 15, lk = (lane >> 4) * 8;
  f32x4 acc[4][4] = {};
  for (int kt = 0; kt < D_MODEL; kt += 64) {
#pragma unroll
    for (int c = 0; c < 4; ++c) {
      const int elem = c * 2048 + t * 8;     // flat bf16 index into 128x64 tile
      const int r = elem >> 6, col = elem & 63;
      GL2LDS(A + (size_t)(tm * 128 + r) * D_MODEL + kt + col, As + c * 2048 + w * 512);
      GL2LDS(B + (size_t)(tn * 128 + r) * D_MODEL + kt + col, Bs + c * 2048 + w * 512);
    }
    __syncthreads();
#pragma unroll
    for (int kk = 0; kk < 2; ++kk) {
      bf16x8 af[4], bfr[4];
#pragma unroll
      for (int i = 0; i < 4; ++i) {
        af[i]  = *(const bf16x8*)(As + (wr * 64 + i * 16 + lrow) * 64 + kk * 32 + lk);
        bfr[i] = *(const bf16x8*)(Bs + (wc * 64 + i * 16 + lrow) * 64 + kk * 32 + lk);
      }
#pragma unroll
      for (int i = 0; i < 4; ++i)
#pragma unroll
        for (int j = 0; j < 4; ++j)
          acc[i][j] = __builtin_amdgcn_mfma_f32_16x16x32_bf16(af[i], bfr[j], acc[i][j], 0, 0, 0);
    }
    __syncthreads();
  }
  // C layout (measured m89): col = lane&15, row = (lane>>4)*4 + reg
  const int crow0 = tm * 128 + wr * 64 + (lane >> 4) * 4;
  const int ccol0 = tn * 128 + wc * 64 + lrow;
  if (outmode == 2) {
#pragma unroll
    for (int i = 0; i < 4; ++i)
#pragma unroll
      for (int j = 0; j < 4; ++j) {
        ushort4 o;
        o.x = f2bf(acc[i][j][0]); o.y = f2bf(acc[i][j][1]);
        o.z = f2bf(acc[i][j][2]); o.w = f2bf(acc[i][j][3]);
        *(ushort4*)((u16*)C + (size_t)(ccol0 + j * 16) * D_MODEL + crow0 + i * 16) = o;
      }
  } else {
#pragma unroll
    for (int i = 0; i < 4; ++i)
#pragma unroll
      for (int j = 0; j < 4; ++j)
#pragma unroll
        for (int r = 0; r < 4; ++r)
          ((u16*)C)[(size_t)(crow0 + i * 16 + r) * D_MODEL + ccol0 + j * 16] = f2bf(acc[i][j][r]);
  }
}

__global__ __launch_bounds__(256) void k_gemm_qkv(const u16* Xq, const u16* Xk, const u16* Xv,
                                                  const u16* Wq, const u16* Wk, const u16* Wv,
                                                  u16* Q, u16* K, u16* VT) {
  __shared__ u16 As[128 * 64], Bs[128 * 64];
  const int z = blockIdx.z;
  const u16* A = (z == 0) ? Xq : (z == 1) ? Xk : Xv;
  const u16* B = (z == 0) ? Wq : (z == 1) ? Wk : Wv;
  u16* C = (z == 0) ? Q : (z == 1) ? K : VT;
  gemm_nt_body(A, B, C, As, Bs, (z == 2) ? 2 : 0);
}

// ---------------- out-proj GEMM: 128x64 tiles -> 512 blocks (2 blocks/CU) ----------------
__global__ __launch_bounds__(256) void k_gemm_out(const u16* __restrict__ A, const u16* __restrict__ B,
                                                  float* __restrict__ C) {
  __shared__ u16 As[128 * 64], Bs[64 * 64];
  const int tn = blockIdx.x, tm = blockIdx.y;
  const int t = threadIdx.x;
  const int lane = t & 63, w = t >> 6;
  const int wr = w >> 1, wc = w & 1;
  const int lrow = lane & 15, lk = (lane >> 4) * 8;
  f32x4 acc[4][2] = {};
  for (int kt = 0; kt < D_MODEL; kt += 64) {
#pragma unroll
    for (int c = 0; c < 4; ++c) {
      const int elem = c * 2048 + t * 8;
      const int r = elem >> 6, col = elem & 63;
      GL2LDS(A + (size_t)(tm * 128 + r) * D_MODEL + kt + col, As + c * 2048 + w * 512);
    }
#pragma unroll
    for (int c = 0; c < 2; ++c) {
      const int elem = c * 2048 + t * 8;
      const int r = elem >> 6, col = elem & 63;
      GL2LDS(B + (size_t)(tn * 64 + r) * D_MODEL + kt + col, Bs + c * 2048 + w * 512);
    }
    __syncthreads();
#pragma unroll
    for (int kk = 0; kk < 2; ++kk) {
      bf16x8 af[4], bfr[2];
#pragma unroll
      for (int i = 0; i < 4; ++i)
        af[i]  = *(const bf16x8*)(As + (wr * 64 + i * 16 + lrow) * 64 + kk * 32 + lk);
#pragma unroll
      for (int j = 0; j < 2; ++j)
        bfr[j] = *(const bf16x8*)(Bs + (wc * 32 + j * 16 + lrow) * 64 + kk * 32 + lk);
#pragma unroll
      for (int i = 0; i < 4; ++i)
#pragma unroll
        for (int j = 0; j < 2; ++j)
          acc[i][j] = __builtin_amdgcn_mfma_f32_16x16x32_bf16(af[i], bfr[j], acc[i][j], 0, 0, 0);
    }
    __syncthreads();
  }
  const int crow0 = tm * 128 + wr * 64 + (lane >> 4) * 4;
  const int ccol0 = tn * 64 + wc * 32 + lrow;
#pragma unroll
  for (int i = 0; i < 4; ++i)
#pragma unroll
    for (int j = 0; j < 2; ++j)
#pragma unroll
      for (int r = 0; r < 4; ++r)
        C[(size_t)(crow0 + i * 16 + r) * D_MODEL + ccol0 + j * 16] = acc[i][j][r];
}

// ---------------- RoPE (rotate_half); Q gets log2(e)/sqrt(hd) for exp2-domain softmax ----------------
__global__ __launch_bounds__(256) void k_rope(u16* Q, u16* K) {
  const int idx = blockIdx.x * blockDim.x + threadIdx.x; // 0 .. SEQ*NHEAD*64-1
  u16* X = blockIdx.y ? K : Q;
  const float scale = blockIdx.y ? 1.0f : (1.4426950408889634f * 0.08838834764831845f);
  const int s = idx >> 10;
  const int h = (idx >> 6) & 15;
  const int j = idx & 63;
  const float freq = __expf((float)j * -0.14391156831212787f); // -ln(10000)/64
  float sn, cs;
  sincosf((float)s * freq, &sn, &cs);
  const size_t base = (size_t)s * D_MODEL + h * HDIM + j;
  const float x1 = bf2f(X[base]), x2 = bf2f(X[base + 64]);
  X[base]      = f2bf((x1 * cs - x2 * sn) * scale);
  X[base + 64] = f2bf((x2 * cs + x1 * sn) * scale);
}

// ---------------- causal flash attention, split-KV ----------------
// 512 blocks x 256 thr. Block bx: head = bx&15, q-tile qt = 31-(bx>>4) (64 rows, longest first).
// 4 waves = 2 M-halves (32 rows) x 2 KV-parities. Parity p computes kv tiles {p, p+2, ...};
// partial (m,l,accO) merged via LDS at the end.
__global__ __launch_bounds__(256, 2) void k_attn(const u16* __restrict__ Q, const u16* __restrict__ K,
                                                 const u16* __restrict__ VT, u16* __restrict__ O) {
  __shared__ u16 Kb[2][64 * 128];   // [parity][row][chunk^ (row&15)]
  __shared__ u16 Vb[2][128 * 64];   // [parity][row][chunk^ (row&7)]
  __shared__ u16 Pl[4][32 * 64];    // per-wave P, chunk ^ (row&7)
  const int bx = blockIdx.x;
  const int h = bx & 15;
  const int qt = 31 - (bx >> 4);
  const int t = threadIdx.x;
  const int lane = t & 63, w = t >> 6;
  const int mh = w & 1, par = w >> 1;
  const int lrow = lane & 15, g = lane >> 4, lk = g * 8;
  const int qrow0 = qt * 64 + mh * 32;

  // Q fragments (Q pre-scaled by log2e/sqrt(128))
  bf16x8 qf[2][4];
#pragma unroll
  for (int mi = 0; mi < 2; ++mi)
#pragma unroll
    for (int ks = 0; ks < 4; ++ks)
      qf[mi][ks] = *(const bf16x8*)(Q + (size_t)(qrow0 + mi * 16 + lrow) * D_MODEL + h * HDIM + ks * 32 + lk);

  f32x4 accO[2][8] = {};
  float m_run[2][4], l_run[2][4];
#pragma unroll
  for (int mi = 0; mi < 2; ++mi)
#pragma unroll
    for (int r = 0; r < 4; ++r) { m_run[mi][r] = -1e30f; l_run[mi][r] = 0.f; }

  const int nt = qt + 1;
  const int nss = (nt + 1) >> 1;
#pragma unroll 1
  for (int s = 0; s < nss; ++s) {
    const int t0 = 2 * s;
    const int t1 = (2 * s + 1 < nt) ? 2 * s + 1 : nt - 1;
    // ---- cooperative stage of both parity tiles (pre-swizzled global source, linear LDS dest) ----
#pragma unroll
    for (int i = 0; i < 4; ++i) {
      const int rk = w * 16 + i * 4 + (lane >> 4);   // K: 4 rows/instr, 16 chunks/row
      const int ck = lane & 15;
      GL2LDS(K + (size_t)(t0 * 64 + rk) * D_MODEL + h * HDIM + ((ck ^ (rk & 15)) * 8),
             Kb[0] + (w * 16 + i * 4) * 128);
      GL2LDS(K + (size_t)(t1 * 64 + rk) * D_MODEL + h * HDIM + ((ck ^ (rk & 15)) * 8),
             Kb[1] + (w * 16 + i * 4) * 128);
      const int rv = w * 32 + i * 8 + (lane >> 3);   // V^T: 8 rows/instr, 8 chunks/row
      const int cv = lane & 7;
      GL2LDS(VT + (size_t)(h * HDIM + rv) * D_MODEL + t0 * 64 + ((cv ^ (rv & 7)) * 8),
             Vb[0] + (w * 32 + i * 8) * 64);
      GL2LDS(VT + (size_t)(h * HDIM + rv) * D_MODEL + t1 * 64 + ((cv ^ (rv & 7)) * 8),
             Vb[1] + (w * 32 + i * 8) * 64);
    }
    __syncthreads();

    const int T = 2 * s + par;
    if (T < nt) {
      // S = Q K^T (32x64), swizzled K reads
      f32x4 sc[2][4] = {};
#pragma unroll
      for (int ks = 0; ks < 4; ++ks) {
        bf16x8 kf[4];
#pragma unroll
        for (int ni = 0; ni < 4; ++ni)
          kf[ni] = *(const bf16x8*)(&Kb[par][(ni * 16 + lrow) * 128 + ((ks * 4 + g) ^ lrow) * 8]);
#pragma unroll
        for (int mi = 0; mi < 2; ++mi)
#pragma unroll
          for (int ni = 0; ni < 4; ++ni)
            sc[mi][ni] = __builtin_amdgcn_mfma_f32_16x16x32_bf16(qf[mi][ks], kf[ni], sc[mi][ni], 0, 0, 0);
      }

      if (T == qt) {   // diagonal tile masking only
        const int kv = T * 64;
#pragma unroll
        for (int mi = 0; mi < 2; ++mi)
#pragma unroll
          for (int ni = 0; ni < 4; ++ni) {
            const int colg = kv + ni * 16 + lrow;
#pragma unroll
            for (int r = 0; r < 4; ++r) {
              const int rowg = qrow0 + mi * 16 + g * 4 + r;
              if (colg > rowg) sc[mi][ni][r] = -1e30f;
            }
          }
      }

      // wave-parallel online softmax (exp2 domain)
#pragma unroll
      for (int mi = 0; mi < 2; ++mi)
#pragma unroll
        for (int r = 0; r < 4; ++r) {
          float pm = fmaxf(fmaxf(sc[mi][0][r], sc[mi][1][r]), fmaxf(sc[mi][2][r], sc[mi][3][r]));
          pm = fmaxf(pm, __shfl_xor(pm, 1));
          pm = fmaxf(pm, __shfl_xor(pm, 2));
          pm = fmaxf(pm, __shfl_xor(pm, 4));
          pm = fmaxf(pm, __shfl_xor(pm, 8));
          const float mo = m_run[mi][r];
          const float mn = fmaxf(mo, pm);
          const float sf = fexp2(mo - mn);
          float rs = 0.f;
#pragma unroll
          for (int ni = 0; ni < 4; ++ni) {
            const float p = fexp2(sc[mi][ni][r] - mn);
            sc[mi][ni][r] = p;
            rs += p;
          }
          rs += __shfl_xor(rs, 1);
          rs += __shfl_xor(rs, 2);
          rs += __shfl_xor(rs, 4);
          rs += __shfl_xor(rs, 8);
          l_run[mi][r] = l_run[mi][r] * sf + rs;
          m_run[mi][r] = mn;
#pragma unroll
          for (int dt = 0; dt < 8; ++dt) accO[mi][dt][r] *= sf;
        }

      // P -> per-wave LDS (swizzled), read back as A-fragments
#pragma unroll
      for (int mi = 0; mi < 2; ++mi)
#pragma unroll
        for (int ni = 0; ni < 4; ++ni)
#pragma unroll
          for (int r = 0; r < 4; ++r) {
            const int row = mi * 16 + g * 4 + r;
            const int chnk = (2 * ni + (lrow >> 3)) ^ (row & 7);
            Pl[w][row * 64 + chnk * 8 + (lrow & 7)] = f2bf(sc[mi][ni][r]);
          }
      asm volatile("s_waitcnt lgkmcnt(0)" ::: "memory");

      // O += P V, swizzled reads
#pragma unroll
      for (int ks2 = 0; ks2 < 2; ++ks2) {
        bf16x8 pf[2];
#pragma unroll
        for (int mi = 0; mi < 2; ++mi) {
          const int row = mi * 16 + lrow;
          pf[mi] = *(const bf16x8*)(&Pl[w][row * 64 + ((ks2 * 4 + g) ^ (row & 7)) * 8]);
        }
#pragma unroll
        for (int dt = 0; dt < 8; ++dt) {
          const int R = dt * 16 + lrow;
          const bf16x8 vf = *(const bf16x8*)(&Vb[par][R * 64 + ((ks2 * 4 + g) ^ (R & 7)) * 8]);
#pragma unroll
          for (int mi = 0; mi < 2; ++mi)
            accO[mi][dt] = __builtin_amdgcn_mfma_f32_16x16x32_bf16(pf[mi], vf, accO[mi][dt], 0, 0, 0);
        }
      }
    }
    __syncthreads();
  }

  // ---- merge the two KV-parity partials (per M-half) via LDS ----
  float* mrg = (float*)&Kb[0][0];           // 2 x (32x128 f32) = 32 KB
  float* mlb = (float*)&Vb[0][0];           // 2 x (32x2 f32)
  if (par == 1) {
#pragma unroll
    for (int mi = 0; mi < 2; ++mi)
#pragma unroll
      for (int dt = 0; dt < 8; ++dt)
#pragma unroll
        for (int r = 0; r < 4; ++r)
          mrg[mh * 4096 + (mi * 16 + g * 4 + r) * 128 + dt * 16 + lrow] = accO[mi][dt][r];
#pragma unroll
    for (int mi = 0; mi < 2; ++mi)
#pragma unroll
      for (int r = 0; r < 4; ++r) {
        const int row = mi * 16 + g * 4 + r;
        mlb[mh * 64 + row * 2]     = m_run[mi][r];
        mlb[mh * 64 + row * 2 + 1] = l_run[mi][r];
      }
  }
  __syncthreads();
  if (par == 0) {
#pragma unroll
    for (int mi = 0; mi < 2; ++mi)
#pragma unroll
      for (int r = 0; r < 4; ++r) {
        const int row = mi * 16 + g * 4 + r;
        const float m1 = mlb[mh * 64 + row * 2];
        const float l1 = mlb[mh * 64 + row * 2 + 1];
        const float mn = fmaxf(m_run[mi][r], m1);
        const float f0 = fexp2(m_run[mi][r] - mn);
        const float f1 = fexp2(m1 - mn);
        const float inv = 1.0f / (l_run[mi][r] * f0 + l1 * f1);
        const size_t grow = (size_t)(qrow0 + row);
#pragma unroll
        for (int dt = 0; dt < 8; ++dt) {
          const float v1 = mrg[mh * 4096 + row * 128 + dt * 16 + lrow];
          O[grow * D_MODEL + h * HDIM + dt * 16 + lrow] =
              f2bf((accO[mi][dt][r] * f0 + v1 * f1) * inv);
        }
      }
  }
}

// ---------------- launch ----------------
extern "C" void kernel_launch(void* const* d_in, const int* in_sizes, int n_in,
                              void* d_out, int out_size, void* d_ws, size_t ws_size,
                              hipStream_t stream) {
  const float* query = (const float*)d_in[0];
  const float* key_  = (const float*)d_in[1];
  const float* value = (const float*)d_in[2];
  const float* Wq    = (const float*)d_in[3];
  const float* Wk    = (const float*)d_in[4];
  const float* Wv    = (const float*)d_in[5];
  const float* Wo    = (const float*)d_in[6];
  float* out = (float*)d_out;

  const size_t TS = (size_t)SEQ * D_MODEL; // 4M elems per tensor
  u16* ws  = (u16*)d_ws;
  u16* bXq = ws + 0 * TS;
  u16* bXk = ws + 1 * TS;
  u16* bXv = ws + 2 * TS;
  u16* bWq = ws + 3 * TS;
  u16* bWk = ws + 4 * TS;
  u16* bWv = ws + 5 * TS;
  u16* bWo = ws + 6 * TS;
  u16* bQ  = ws + 7 * TS;
  u16* bK  = ws + 8 * TS;
  u16* bVT = ws + 9 * TS;
  u16* bA  = ws + 10 * TS;

  const int n4 = (int)(TS / 4);
  k_cast7<<<dim3(n4 / 256, 7), 256, 0, stream>>>(query, key_, value, Wq, Wk, Wv, Wo,
                                                 bXq, bXk, bXv, bWq, bWk, bWv, bWo);

  k_gemm_qkv<<<dim3(16, 16, 3), 256, 0, stream>>>(bXq, bXk, bXv, bWq, bWk, bWv, bQ, bK, bVT);

  k_rope<<<dim3((SEQ * NHEAD * 64) / 256, 2), 256, 0, stream>>>(bQ, bK);

  k_attn<<<dim3(512), 256, 0, stream>>>(bQ, bK, bVT, bA);

  k_gemm_out<<<dim3(32, 16), 256, 0, stream>>>(bA, bWo, out);
}

// Round 4
// 310.235 us; speedup vs baseline: 1.3638x; 1.1328x over previous
//
#include <hip/hip_runtime.h>

typedef unsigned short u16;
typedef __attribute__((ext_vector_type(8))) __bf16 bf16x8;
typedef __attribute__((ext_vector_type(4))) float f32x4;

#define D_MODEL 2048
#define SEQ 2048
#define NHEAD 16
#define HDIM 128

#define AS1 __attribute__((address_space(1)))
#define AS3 __attribute__((address_space(3)))
#define GL2LDS(g, l) __builtin_amdgcn_global_load_lds((AS1 const void*)(g), (AS3 void*)(l), 16, 0, 0)

__device__ __forceinline__ u16 f2bf(float f) {
  unsigned u = __float_as_uint(f);
  u += 0x7fff + ((u >> 16) & 1);   // RNE
  return (u16)(u >> 16);
}
__device__ __forceinline__ float bf2f(u16 h) {
  return __uint_as_float(((unsigned)h) << 16);
}
__device__ __forceinline__ float fexp2(float x) {
#if __has_builtin(__builtin_amdgcn_exp2f)
  return __builtin_amdgcn_exp2f(x);
#else
  return __expf(x * 0.69314718055994531f);
#endif
}

// ---------------- fused fp32 -> bf16 casts (7 tensors, one launch) ----------------
__global__ __launch_bounds__(256) void k_cast7(const float* i0, const float* i1, const float* i2,
                                               const float* i3, const float* i4, const float* i5,
                                               const float* i6,
                                               u16* o0, u16* o1, u16* o2, u16* o3, u16* o4,
                                               u16* o5, u16* o6) {
  const float* in; u16* out;
  switch (blockIdx.y) {
    case 0: in = i0; out = o0; break;
    case 1: in = i1; out = o1; break;
    case 2: in = i2; out = o2; break;
    case 3: in = i3; out = o3; break;
    case 4: in = i4; out = o4; break;
    case 5: in = i5; out = o5; break;
    default: in = i6; out = o6; break;
  }
  const int i = blockIdx.x * blockDim.x + threadIdx.x;
  const float4 v = reinterpret_cast<const float4*>(in)[i];
  ushort4 o;
  o.x = f2bf(v.x); o.y = f2bf(v.y); o.z = f2bf(v.z); o.w = f2bf(v.w);
  reinterpret_cast<ushort4*>(out)[i] = o;
}

// ---------------- GEMM staging: 128x64 tile, rows of 8 chunks, chunk ^= (row&7) swizzle ----------------
// LDS dest linear (gl2lds requirement); global SOURCE pre-swizzled; reads apply same XOR (rule #21).
__device__ __forceinline__ void stage128(const u16* __restrict__ P, u16* dst, int row0, int kt,
                                         int t, int w) {
#pragma unroll
  for (int c = 0; c < 4; ++c) {
    const int r = (c * 2048 + t * 8) >> 6;            // tile row 0..127
    const int ch = ((t & 7) ^ (r & 7)) * 8;           // swizzled k-chunk
    GL2LDS(P + (size_t)(row0 + r) * D_MODEL + kt + ch, dst + c * 2048 + w * 512);
  }
}
__device__ __forceinline__ void stage64(const u16* __restrict__ P, u16* dst, int row0, int kt,
                                        int t, int w) {
#pragma unroll
  for (int c = 0; c < 2; ++c) {
    const int r = (c * 2048 + t * 8) >> 6;            // tile row 0..63
    const int ch = ((t & 7) ^ (r & 7)) * 8;
    GL2LDS(P + (size_t)(row0 + r) * D_MODEL + kt + ch, dst + c * 2048 + w * 512);
  }
}

// ---------------- NT GEMM: C[m,n] = sum_k A[m,k]*B[n,k], 128x128 tile, dbuf prefetch ----------------
// outmode: 0 = bf16 row-major, 2 = bf16 TRANSPOSED (out[n][m])
__device__ __forceinline__ void gemm_nt_body(const u16* __restrict__ A, const u16* __restrict__ B,
                                             void* __restrict__ C, u16* As0, u16* As1,
                                             u16* Bs0, u16* Bs1, int outmode) {
  const int tn = blockIdx.x, tm = blockIdx.y;
  const int t = threadIdx.x;
  const int lane = t & 63, w = t >> 6;
  const int wr = w >> 1, wc = w & 1;
  const int lrow = lane & 15, g = lane >> 4;
  f32x4 acc[4][4] = {};

  stage128(A, As0, tm * 128, 0, t, w);
  stage128(B, Bs0, tn * 128, 0, t, w);
  __syncthreads();

  u16 *Ar = As0, *Br = Bs0, *Aw = As1, *Bw = Bs1;
#pragma unroll 1
  for (int kt = 0; kt < D_MODEL; kt += 64) {
    if (kt + 64 < D_MODEL) {           // issue next-tile loads BEFORE compute (T3-minimum)
      stage128(A, Aw, tm * 128, kt + 64, t, w);
      stage128(B, Bw, tn * 128, kt + 64, t, w);
    }
#pragma unroll
    for (int kk = 0; kk < 2; ++kk) {
      bf16x8 af[4], bfr[4];
#pragma unroll
      for (int i = 0; i < 4; ++i) {
        const int sw = (((kk << 2) + g) ^ (lrow & 7)) * 8;
        af[i]  = *(const bf16x8*)(Ar + (wr * 64 + i * 16 + lrow) * 64 + sw);
        bfr[i] = *(const bf16x8*)(Br + (wc * 64 + i * 16 + lrow) * 64 + sw);
      }
#pragma unroll
      for (int i = 0; i < 4; ++i)
#pragma unroll
        for (int j = 0; j < 4; ++j)
          acc[i][j] = __builtin_amdgcn_mfma_f32_16x16x32_bf16(af[i], bfr[j], acc[i][j], 0, 0, 0);
    }
    __syncthreads();                   // drains vmcnt (next buf landed) + all reads of cur done
    u16* tp;
    tp = Ar; Ar = Aw; Aw = tp;
    tp = Br; Br = Bw; Bw = tp;
  }

  // C layout (measured m89): col = lane&15, row = (lane>>4)*4 + reg
  const int crow0 = tm * 128 + wr * 64 + (lane >> 4) * 4;
  const int ccol0 = tn * 128 + wc * 64 + lrow;
  if (outmode == 2) {
#pragma unroll
    for (int i = 0; i < 4; ++i)
#pragma unroll
      for (int j = 0; j < 4; ++j) {
        ushort4 o;
        o.x = f2bf(acc[i][j][0]); o.y = f2bf(acc[i][j][1]);
        o.z = f2bf(acc[i][j][2]); o.w = f2bf(acc[i][j][3]);
        *(ushort4*)((u16*)C + (size_t)(ccol0 + j * 16) * D_MODEL + crow0 + i * 16) = o;
      }
  } else {
#pragma unroll
    for (int i = 0; i < 4; ++i)
#pragma unroll
      for (int j = 0; j < 4; ++j)
#pragma unroll
        for (int r = 0; r < 4; ++r)
          ((u16*)C)[(size_t)(crow0 + i * 16 + r) * D_MODEL + ccol0 + j * 16] = f2bf(acc[i][j][r]);
  }
}

__global__ __launch_bounds__(256, 2) void k_gemm_qkv(const u16* Xq, const u16* Xk, const u16* Xv,
                                                     const u16* Wq, const u16* Wk, const u16* Wv,
                                                     u16* Q, u16* K, u16* VT) {
  __shared__ u16 As[2][128 * 64], Bs[2][128 * 64];
  const int z = blockIdx.z;
  const u16* A = (z == 0) ? Xq : (z == 1) ? Xk : Xv;
  const u16* B = (z == 0) ? Wq : (z == 1) ? Wk : Wv;
  u16* C = (z == 0) ? Q : (z == 1) ? K : VT;
  gemm_nt_body(A, B, C, As[0], As[1], Bs[0], Bs[1], (z == 2) ? 2 : 0);
}

// ---------------- out-proj GEMM: 128x64 tiles -> 512 blocks, dbuf prefetch ----------------
__global__ __launch_bounds__(256, 2) void k_gemm_out(const u16* __restrict__ A, const u16* __restrict__ B,
                                                     float* __restrict__ C) {
  __shared__ u16 As[2][128 * 64], Bs[2][64 * 64];
  const int tn = blockIdx.x, tm = blockIdx.y;
  const int t = threadIdx.x;
  const int lane = t & 63, w = t >> 6;
  const int wr = w >> 1, wc = w & 1;
  const int lrow = lane & 15, g = lane >> 4;
  f32x4 acc[4][2] = {};

  stage128(A, As[0], tm * 128, 0, t, w);
  stage64(B, Bs[0], tn * 64, 0, t, w);
  __syncthreads();

  u16 *Ar = As[0], *Br = Bs[0], *Aw = As[1], *Bw = Bs[1];
#pragma unroll 1
  for (int kt = 0; kt < D_MODEL; kt += 64) {
    if (kt + 64 < D_MODEL) {
      stage128(A, Aw, tm * 128, kt + 64, t, w);
      stage64(B, Bw, tn * 64, kt + 64, t, w);
    }
#pragma unroll
    for (int kk = 0; kk < 2; ++kk) {
      bf16x8 af[4], bfr[2];
#pragma unroll
      for (int i = 0; i < 4; ++i) {
        const int sw = (((kk << 2) + g) ^ (lrow & 7)) * 8;
        af[i] = *(const bf16x8*)(Ar + (wr * 64 + i * 16 + lrow) * 64 + sw);
        if (i < 2) bfr[i] = *(const bf16x8*)(Br + (wc * 32 + i * 16 + lrow) * 64 + sw);
      }
#pragma unroll
      for (int i = 0; i < 4; ++i)
#pragma unroll
        for (int j = 0; j < 2; ++j)
          acc[i][j] = __builtin_amdgcn_mfma_f32_16x16x32_bf16(af[i], bfr[j], acc[i][j], 0, 0, 0);
    }
    __syncthreads();
    u16* tp;
    tp = Ar; Ar = Aw; Aw = tp;
    tp = Br; Br = Bw; Bw = tp;
  }
  const int crow0 = tm * 128 + wr * 64 + (lane >> 4) * 4;
  const int ccol0 = tn * 64 + wc * 32 + lrow;
#pragma unroll
  for (int i = 0; i < 4; ++i)
#pragma unroll
    for (int j = 0; j < 2; ++j)
#pragma unroll
      for (int r = 0; r < 4; ++r)
        C[(size_t)(crow0 + i * 16 + r) * D_MODEL + ccol0 + j * 16] = acc[i][j][r];
}

// ---------------- RoPE (rotate_half); Q gets log2(e)/sqrt(hd) for exp2-domain softmax ----------------
__global__ __launch_bounds__(256) void k_rope(u16* Q, u16* K) {
  const int idx = blockIdx.x * blockDim.x + threadIdx.x; // 0 .. SEQ*NHEAD*64-1
  u16* X = blockIdx.y ? K : Q;
  const float scale = blockIdx.y ? 1.0f : (1.4426950408889634f * 0.08838834764831845f);
  const int s = idx >> 10;
  const int h = (idx >> 6) & 15;
  const int j = idx & 63;
  const float freq = __expf((float)j * -0.14391156831212787f); // -ln(10000)/64
  float sn, cs;
  sincosf((float)s * freq, &sn, &cs);
  const size_t base = (size_t)s * D_MODEL + h * HDIM + j;
  const float x1 = bf2f(X[base]), x2 = bf2f(X[base + 64]);
  X[base]      = f2bf((x1 * cs - x2 * sn) * scale);
  X[base + 64] = f2bf((x2 * cs + x1 * sn) * scale);
}

// ---------------- causal flash attention, split-KV ----------------
// 512 blocks x 256 thr. Block bx: head = bx&15, q-tile qt = 31-(bx>>4) (64 rows, longest first).
// 4 waves = 2 M-halves (32 rows) x 2 KV-parities; partials merged via LDS at the end.
__global__ __launch_bounds__(256, 2) void k_attn(const u16* __restrict__ Q, const u16* __restrict__ K,
                                                 const u16* __restrict__ VT, u16* __restrict__ O) {
  __shared__ u16 Kb[2][64 * 128];   // [parity][row][chunk ^ (row&15)]
  __shared__ u16 Vb[2][128 * 64];   // [parity][row][chunk ^ (row&7)]
  __shared__ u16 Pl[4][32 * 64];    // per-wave P, chunk ^ (row&7)
  const int bx = blockIdx.x;
  const int h = bx & 15;
  const int qt = 31 - (bx >> 4);
  const int t = threadIdx.x;
  const int lane = t & 63, w = t >> 6;
  const int mh = w & 1, par = w >> 1;
  const int lrow = lane & 15, g = lane >> 4, lk = g * 8;
  const int qrow0 = qt * 64 + mh * 32;

  bf16x8 qf[2][4];
#pragma unroll
  for (int mi = 0; mi < 2; ++mi)
#pragma unroll
    for (int ks = 0; ks < 4; ++ks)
      qf[mi][ks] = *(const bf16x8*)(Q + (size_t)(qrow0 + mi * 16 + lrow) * D_MODEL + h * HDIM + ks * 32 + lk);

  f32x4 accO[2][8] = {};
  float m_run[2][4], l_run[2][4];
#pragma unroll
  for (int mi = 0; mi < 2; ++mi)
#pragma unroll
    for (int r = 0; r < 4; ++r) { m_run[mi][r] = -1e30f; l_run[mi][r] = 0.f; }

  const int nt = qt + 1;
  const int nss = (nt + 1) >> 1;
#pragma unroll 1
  for (int s = 0; s < nss; ++s) {
    const int t0 = 2 * s;
    const int t1 = (2 * s + 1 < nt) ? 2 * s + 1 : nt - 1;
#pragma unroll
    for (int i = 0; i < 4; ++i) {
      const int rk = w * 16 + i * 4 + (lane >> 4);
      const int ck = lane & 15;
      GL2LDS(K + (size_t)(t0 * 64 + rk) * D_MODEL + h * HDIM + ((ck ^ (rk & 15)) * 8),
             Kb[0] + (w * 16 + i * 4) * 128);
      GL2LDS(K + (size_t)(t1 * 64 + rk) * D_MODEL + h * HDIM + ((ck ^ (rk & 15)) * 8),
             Kb[1] + (w * 16 + i * 4) * 128);
      const int rv = w * 32 + i * 8 + (lane >> 3);
      const int cv = lane & 7;
      GL2LDS(VT + (size_t)(h * HDIM + rv) * D_MODEL + t0 * 64 + ((cv ^ (rv & 7)) * 8),
             Vb[0] + (w * 32 + i * 8) * 64);
      GL2LDS(VT + (size_t)(h * HDIM + rv) * D_MODEL + t1 * 64 + ((cv ^ (rv & 7)) * 8),
             Vb[1] + (w * 32 + i * 8) * 64);
    }
    __syncthreads();

    const int T = 2 * s + par;
    if (T < nt) {
      f32x4 sc[2][4] = {};
#pragma unroll
      for (int ks = 0; ks < 4; ++ks) {
        bf16x8 kf[4];
#pragma unroll
        for (int ni = 0; ni < 4; ++ni)
          kf[ni] = *(const bf16x8*)(&Kb[par][(ni * 16 + lrow) * 128 + ((ks * 4 + g) ^ lrow) * 8]);
#pragma unroll
        for (int mi = 0; mi < 2; ++mi)
#pragma unroll
          for (int ni = 0; ni < 4; ++ni)
            sc[mi][ni] = __builtin_amdgcn_mfma_f32_16x16x32_bf16(qf[mi][ks], kf[ni], sc[mi][ni], 0, 0, 0);
      }

      if (T == qt) {
        const int kv = T * 64;
#pragma unroll
        for (int mi = 0; mi < 2; ++mi)
#pragma unroll
          for (int ni = 0; ni < 4; ++ni) {
            const int colg = kv + ni * 16 + lrow;
#pragma unroll
            for (int r = 0; r < 4; ++r) {
              const int rowg = qrow0 + mi * 16 + g * 4 + r;
              if (colg > rowg) sc[mi][ni][r] = -1e30f;
            }
          }
      }

#pragma unroll
      for (int mi = 0; mi < 2; ++mi)
#pragma unroll
        for (int r = 0; r < 4; ++r) {
          float pm = fmaxf(fmaxf(sc[mi][0][r], sc[mi][1][r]), fmaxf(sc[mi][2][r], sc[mi][3][r]));
          pm = fmaxf(pm, __shfl_xor(pm, 1));
          pm = fmaxf(pm, __shfl_xor(pm, 2));
          pm = fmaxf(pm, __shfl_xor(pm, 4));
          pm = fmaxf(pm, __shfl_xor(pm, 8));
          const float mo = m_run[mi][r];
          const float mn = fmaxf(mo, pm);
          const float sf = fexp2(mo - mn);
          float rs = 0.f;
#pragma unroll
          for (int ni = 0; ni < 4; ++ni) {
            const float p = fexp2(sc[mi][ni][r] - mn);
            sc[mi][ni][r] = p;
            rs += p;
          }
          rs += __shfl_xor(rs, 1);
          rs += __shfl_xor(rs, 2);
          rs += __shfl_xor(rs, 4);
          rs += __shfl_xor(rs, 8);
          l_run[mi][r] = l_run[mi][r] * sf + rs;
          m_run[mi][r] = mn;
#pragma unroll
          for (int dt = 0; dt < 8; ++dt) accO[mi][dt][r] *= sf;
        }

#pragma unroll
      for (int mi = 0; mi < 2; ++mi)
#pragma unroll
        for (int ni = 0; ni < 4; ++ni)
#pragma unroll
          for (int r = 0; r < 4; ++r) {
            const int row = mi * 16 + g * 4 + r;
            const int chnk = (2 * ni + (lrow >> 3)) ^ (row & 7);
            Pl[w][row * 64 + chnk * 8 + (lrow & 7)] = f2bf(sc[mi][ni][r]);
          }
      asm volatile("s_waitcnt lgkmcnt(0)" ::: "memory");

#pragma unroll
      for (int ks2 = 0; ks2 < 2; ++ks2) {
        bf16x8 pf[2];
#pragma unroll
        for (int mi = 0; mi < 2; ++mi) {
          const int row = mi * 16 + lrow;
          pf[mi] = *(const bf16x8*)(&Pl[w][row * 64 + ((ks2 * 4 + g) ^ (row & 7)) * 8]);
        }
#pragma unroll
        for (int dt = 0; dt < 8; ++dt) {
          const int R = dt * 16 + lrow;
          const bf16x8 vf = *(const bf16x8*)(&Vb[par][R * 64 + ((ks2 * 4 + g) ^ (R & 7)) * 8]);
#pragma unroll
          for (int mi = 0; mi < 2; ++mi)
            accO[mi][dt] = __builtin_amdgcn_mfma_f32_16x16x32_bf16(pf[mi], vf, accO[mi][dt], 0, 0, 0);
        }
      }
    }
    __syncthreads();
  }

  float* mrg = (float*)&Kb[0][0];
  float* mlb = (float*)&Vb[0][0];
  if (par == 1) {
#pragma unroll
    for (int mi = 0; mi < 2; ++mi)
#pragma unroll
      for (int dt = 0; dt < 8; ++dt)
#pragma unroll
        for (int r = 0; r < 4; ++r)
          mrg[mh * 4096 + (mi * 16 + g * 4 + r) * 128 + dt * 16 + lrow] = accO[mi][dt][r];
#pragma unroll
    for (int mi = 0; mi < 2; ++mi)
#pragma unroll
      for (int r = 0; r < 4; ++r) {
        const int row = mi * 16 + g * 4 + r;
        mlb[mh * 64 + row * 2]     = m_run[mi][r];
        mlb[mh * 64 + row * 2 + 1] = l_run[mi][r];
      }
  }
  __syncthreads();
  if (par == 0) {
#pragma unroll
    for (int mi = 0; mi < 2; ++mi)
#pragma unroll
      for (int r = 0; r < 4; ++r) {
        const int row = mi * 16 + g * 4 + r;
        const float m1 = mlb[mh * 64 + row * 2];
        const float l1 = mlb[mh * 64 + row * 2 + 1];
        const float mn = fmaxf(m_run[mi][r], m1);
        const float f0 = fexp2(m_run[mi][r] - mn);
        const float f1 = fexp2(m1 - mn);
        const float inv = 1.0f / (l_run[mi][r] * f0 + l1 * f1);
        const size_t grow = (size_t)(qrow0 + row);
#pragma unroll
        for (int dt = 0; dt < 8; ++dt) {
          const float v1 = mrg[mh * 4096 + row * 128 + dt * 16 + lrow];
          O[grow * D_MODEL + h * HDIM + dt * 16 + lrow] =
              f2bf((accO[mi][dt][r] * f0 + v1 * f1) * inv);
        }
      }
  }
}

// ---------------- launch ----------------
extern "C" void kernel_launch(void* const* d_in, const int* in_sizes, int n_in,
                              void* d_out, int out_size, void* d_ws, size_t ws_size,
                              hipStream_t stream) {
  const float* query = (const float*)d_in[0];
  const float* key_  = (const float*)d_in[1];
  const float* value = (const float*)d_in[2];
  const float* Wq    = (const float*)d_in[3];
  const float* Wk    = (const float*)d_in[4];
  const float* Wv    = (const float*)d_in[5];
  const float* Wo    = (const float*)d_in[6];
  float* out = (float*)d_out;

  const size_t TS = (size_t)SEQ * D_MODEL; // 4M elems per tensor
  u16* ws  = (u16*)d_ws;
  u16* bXq = ws + 0 * TS;
  u16* bXk = ws + 1 * TS;
  u16* bXv = ws + 2 * TS;
  u16* bWq = ws + 3 * TS;
  u16* bWk = ws + 4 * TS;
  u16* bWv = ws + 5 * TS;
  u16* bWo = ws + 6 * TS;
  u16* bQ  = ws + 7 * TS;
  u16* bK  = ws + 8 * TS;
  u16* bVT = ws + 9 * TS;
  u16* bA  = ws + 10 * TS;

  const int n4 = (int)(TS / 4);
  k_cast7<<<dim3(n4 / 256, 7), 256, 0, stream>>>(query, key_, value, Wq, Wk, Wv, Wo,
                                                 bXq, bXk, bXv, bWq, bWk, bWv, bWo);

  k_gemm_qkv<<<dim3(16, 16, 3), 256, 0, stream>>>(bXq, bXk, bXv, bWq, bWk, bWv, bQ, bK, bVT);

  k_rope<<<dim3((SEQ * NHEAD * 64) / 256, 2), 256, 0, stream>>>(bQ, bK);

  k_attn<<<dim3(512), 256, 0, stream>>>(bQ, bK, bVT, bA);

  k_gemm_out<<<dim3(32, 16), 256, 0, stream>>>(bA, bWo, out);
}